// Round 7
// baseline (138.126 us; speedup 1.0000x reference)
//
#include <hip/hip_runtime.h>

#define ED 256
#define NHEAD 8
#define NPTS 8
#define DHEAD 32
#define QPB 8   // queries per block: 4 waves x 2 queries (one per 32-lane half)

typedef _Float16 half8v __attribute__((ext_vector_type(8)));

// ---------------------------------------------------------------------------
// Kernel C v2: feat fp32 -> fp16, XCD-pinned. blk % bs = batch -> the blocks
// converting batch b run on XCD b and leave its 2MB fp16 map resident in XCD
// b's L2 (write-back allocates in the writer's XCD). deform's batch-b blocks
// (same swizzle) then hit LOCAL L2 instead of cross-XCD/L3.
// 32B per thread-iter: 2x float4 load -> 1x half8v store.
// ---------------------------------------------------------------------------
__global__ __launch_bounds__(256) void convert_kernel(
    const float4* __restrict__ feat, half8v* __restrict__ feat16,
    int per_batch8, int bs)
{
    const int b      = blockIdx.x % bs;
    const int chunk  = blockIdx.x / bs;
    const int nchunk = gridDim.x / bs;
    const size_t base = (size_t)b * per_batch8;

    for (int i = chunk * 256 + threadIdx.x; i < per_batch8; i += nchunk * 256) {
        const size_t idx = base + i;
        const float4 f0 = feat[2 * idx];
        const float4 f1 = feat[2 * idx + 1];
        half8v h;
        h[0] = (_Float16)f0.x; h[1] = (_Float16)f0.y;
        h[2] = (_Float16)f0.z; h[3] = (_Float16)f0.w;
        h[4] = (_Float16)f1.x; h[5] = (_Float16)f1.y;
        h[6] = (_Float16)f1.z; h[7] = (_Float16)f1.w;
        feat16[idx] = h;
    }
}

// ---------------------------------------------------------------------------
// Kernel A: per-batch precompute (query is [bs,1,ED] broadcast -> offsets and
// softmax weights depend only on batch). K-split matvecs + LDS reduce.
// ws layout per batch: off[128] then aw[64] (192 floats).
// ---------------------------------------------------------------------------
__global__ __launch_bounds__(256) void precompute_kernel(
    const float* __restrict__ query,
    const float* __restrict__ W_off, const float* __restrict__ b_off,
    const float* __restrict__ W_attn, const float* __restrict__ b_attn,
    float* __restrict__ ws)
{
    const int b = blockIdx.x;
    const int t = threadIdx.x;
    __shared__ float sq[ED];
    __shared__ float red[256];
    __shared__ float sattn[64];

    sq[t] = query[b * ED + t];
    __syncthreads();

    {
        const int col  = t & 127;
        const int half = t >> 7;
        const float* Wp = W_off + (size_t)half * 128 * 128 + col;
        const float* qp = sq + half * 128;
        float a0 = 0.f, a1 = 0.f, a2 = 0.f, a3 = 0.f;
        #pragma unroll 8
        for (int k = 0; k < 128; k += 4) {
            a0 = fmaf(qp[k + 0], Wp[(k + 0) * 128], a0);
            a1 = fmaf(qp[k + 1], Wp[(k + 1) * 128], a1);
            a2 = fmaf(qp[k + 2], Wp[(k + 2) * 128], a2);
            a3 = fmaf(qp[k + 3], Wp[(k + 3) * 128], a3);
        }
        red[t] = (a0 + a1) + (a2 + a3);
    }
    __syncthreads();
    if (t < 128) ws[b * 192 + t] = fmaxf(red[t] + red[t + 128] + b_off[t], 0.0f);
    __syncthreads();

    {
        const int col = t & 63;
        const int qtr = t >> 6;
        const float* Wp = W_attn + (size_t)qtr * 64 * 64 + col;
        const float* qp = sq + qtr * 64;
        float a0 = 0.f, a1 = 0.f, a2 = 0.f, a3 = 0.f;
        #pragma unroll 8
        for (int k = 0; k < 64; k += 4) {
            a0 = fmaf(qp[k + 0], Wp[(k + 0) * 64], a0);
            a1 = fmaf(qp[k + 1], Wp[(k + 1) * 64], a1);
            a2 = fmaf(qp[k + 2], Wp[(k + 2) * 64], a2);
            a3 = fmaf(qp[k + 3], Wp[(k + 3) * 64], a3);
        }
        red[t] = (a0 + a1) + (a2 + a3);
    }
    __syncthreads();
    if (t < 64) {
        sattn[t] = fmaxf(red[t] + red[t + 64] + red[t + 128] + red[t + 192]
                         + b_attn[t], 0.0f);
    }
    __syncthreads();
    if (t < 64) {
        const int hh = t >> 3;
        float m = -1e30f;
        #pragma unroll
        for (int p = 0; p < NPTS; ++p) m = fmaxf(m, sattn[hh * NPTS + p]);
        float s = 0.0f;
        #pragma unroll
        for (int p = 0; p < NPTS; ++p) s += expf(sattn[hh * NPTS + p] - m);
        ws[b * 192 + 128 + t] = expf(sattn[t] - m) / s;
    }
}

// ---------------------------------------------------------------------------
// Kernel B v7 = v6 + __launch_bounds__(256,6).
// v6's (256,4) capped occupancy at 16 waves/CU (measured ~53%); the kernel is
// latency-bound on the L2 gather path, so 24 waves/CU of TLP is worth more
// than the wider VGPR budget (need ~60 regs, cap is 85 -> no spill).
//  - wave = 2 queries (one per 32-lane half); thread = 8 fp16 channels.
//  - per point-pair batch: 4 ds_read_b128 + 8 global dwordx4 + 64 fma_mix.
//  - LayerNorm reduce over 32 lanes (shfl_xor m<=16 stays in-half).
//  - blockIdx % bs pins batch b to XCD b (matches convert's placement).
// ---------------------------------------------------------------------------
__global__ __launch_bounds__(256, 6) void deform_attn_kernel(
    const _Float16* __restrict__ feat16, // [bs, nq, NHEAD, DHEAD] fp16
    const float* __restrict__ ref2d,     // [bs, nq, 1, 2]
    const float* __restrict__ query,     // [bs, 1, ED]
    const float* __restrict__ ln_g, const float* __restrict__ ln_b,
    const float* __restrict__ ws,        // [bs, 192]
    const int* __restrict__ Hp, const int* __restrict__ Wp,
    float* __restrict__ out,             // [bs, nq, ED]
    int nq, int bs)
{
    const int blk = blockIdx.x;
    const int b = blk % bs;                    // XCD swizzle
    const int qbase = (blk / bs) * QPB;
    const int t = threadIdx.x;

    __shared__ float s_off[128];
    __shared__ float s_aw[64];
    __shared__ float s_ref[QPB * 2];
    __shared__ uint4  s_ofs[QPB * 64];         // [q][p*8+h]: byte offsets
    __shared__ float4 s_wt [QPB * 64];         // [q][p*8+h]: folded weights

    if (t < 128)      s_off[t] = ws[b * 192 + t];
    else if (t < 192) s_aw[t - 128] = ws[b * 192 + t];
    else if (t < 192 + QPB * 2) {
        const int i = t - 192;                 // i = qL*2 + j
        s_ref[i] = ref2d[(b * nq + qbase + (i >> 1)) * 2 + (i & 1)];
    }
    const int H = Hp[0];
    const int W = Wp[0];
    __syncthreads();

    // ---- Phase 1: 8*64 tuples, 2 per thread; entry l -> (p=l>>3, h=l&7) ----
    #pragma unroll
    for (int u = t; u < QPB * 64; u += 256) {
        const int qL = u >> 6;
        const int l  = u & 63;
        const int p  = l >> 3;
        const int h  = l & 7;
        const int hp = h * 8 + p;

        const float x = s_ref[qL * 2 + 0] * (float)W - 0.5f + s_off[hp * 2 + 0];
        const float y = s_ref[qL * 2 + 1] * (float)H - 0.5f + s_off[hp * 2 + 1];
        const float aw = s_aw[hp];

        const float xf = floorf(x);
        const float yf = floorf(y);
        const int ix = (int)xf;
        const int iy = (int)yf;
        const float wx = x - xf;
        const float wy = y - yf;

        const bool vx0 = (ix >= 0) && (ix < W);
        const bool vx1 = (ix + 1 >= 0) && (ix + 1 < W);
        const bool vy0 = (iy >= 0) && (iy < H);
        const bool vy1 = (iy + 1 >= 0) && (iy + 1 < H);
        const int cx0 = min(max(ix, 0), W - 1);
        const int cx1 = min(max(ix + 1, 0), W - 1);
        const int cy0 = min(max(iy, 0), H - 1);
        const int cy1 = min(max(iy + 1, 0), H - 1);

        const int r0 = cy0 * W;
        const int r1 = cy1 * W;
        uint4 ofs;                              // byte offsets, pos stride 512B
        ofs.x = (unsigned)(r0 + cx0) << 9;
        ofs.y = (unsigned)(r0 + cx1) << 9;
        ofs.z = (unsigned)(r1 + cx0) << 9;
        ofs.w = (unsigned)(r1 + cx1) << 9;

        const float awx = aw * wx, awix = aw - awx;     // aw*(1-wx)
        float4 wt;
        wt.x = (vx0 && vy0) ? awix * (1.0f - wy) : 0.0f;
        wt.y = (vx1 && vy0) ? awx  * (1.0f - wy) : 0.0f;
        wt.z = (vx0 && vy1) ? awix * wy          : 0.0f;
        wt.w = (vx1 && vy1) ? awx  * wy          : 0.0f;

        s_ofs[u] = ofs;
        s_wt[u]  = wt;
    }
    __syncthreads();

    // ---- Phase 2: gather. wave = 2 queries; thread = 8 channels ----
    const int wave = t >> 6;
    const int lane = t & 63;
    const int half = lane >> 5;
    const int l32  = lane & 31;
    const int h    = l32 >> 2;                 // head
    const int c16  = l32 & 3;                  // 16B chunk within 64B slice
    const int qloc = wave * 2 + half;
    const int q    = qbase + qloc;
    const int cb   = qloc * 64 + h;            // + p*8 per point

    const char* fb = (const char*)feat16 + (size_t)b * nq * (NHEAD * DHEAD * 2);
    const unsigned laneofs = (unsigned)(h * 64 + c16 * 16);

    float acc[8] = {0.f, 0.f, 0.f, 0.f, 0.f, 0.f, 0.f, 0.f};

    #pragma unroll
    for (int pp = 0; pp < NPTS; pp += 2) {
        const uint4  iA = s_ofs[cb + pp * 8];
        const float4 wA = s_wt [cb + pp * 8];
        const uint4  iB = s_ofs[cb + pp * 8 + 8];
        const float4 wB = s_wt [cb + pp * 8 + 8];

        const half8v a0 = *(const half8v*)(fb + (iA.x + laneofs));
        const half8v a1 = *(const half8v*)(fb + (iA.y + laneofs));
        const half8v a2 = *(const half8v*)(fb + (iA.z + laneofs));
        const half8v a3 = *(const half8v*)(fb + (iA.w + laneofs));
        const half8v b0 = *(const half8v*)(fb + (iB.x + laneofs));
        const half8v b1 = *(const half8v*)(fb + (iB.y + laneofs));
        const half8v b2 = *(const half8v*)(fb + (iB.z + laneofs));
        const half8v b3 = *(const half8v*)(fb + (iB.w + laneofs));

        #pragma unroll
        for (int j = 0; j < 8; ++j) {
            acc[j] = fmaf(wA.x, (float)a0[j], acc[j]);
            acc[j] = fmaf(wA.y, (float)a1[j], acc[j]);
            acc[j] = fmaf(wA.z, (float)a2[j], acc[j]);
            acc[j] = fmaf(wA.w, (float)a3[j], acc[j]);
            acc[j] = fmaf(wB.x, (float)b0[j], acc[j]);
            acc[j] = fmaf(wB.y, (float)b1[j], acc[j]);
            acc[j] = fmaf(wB.z, (float)b2[j], acc[j]);
            acc[j] = fmaf(wB.w, (float)b3[j], acc[j]);
        }
    }

    // ---- Phase 3: residual + half-wave (32-lane) LayerNorm ----
    const float4 qv0 = *(const float4*)(query + b * ED + l32 * 8);
    const float4 qv1 = *(const float4*)(query + b * ED + l32 * 8 + 4);
    float r[8];
    r[0] = acc[0] + qv0.x; r[1] = acc[1] + qv0.y;
    r[2] = acc[2] + qv0.z; r[3] = acc[3] + qv0.w;
    r[4] = acc[4] + qv1.x; r[5] = acc[5] + qv1.y;
    r[6] = acc[6] + qv1.z; r[7] = acc[7] + qv1.w;

    float s = 0.f, ss = 0.f;
    #pragma unroll
    for (int j = 0; j < 8; ++j) {
        s += r[j];
        ss = fmaf(r[j], r[j], ss);
    }
    #pragma unroll
    for (int m = 1; m < 32; m <<= 1) {         // stays within 32-lane half
        s  += __shfl_xor(s, m, 64);
        ss += __shfl_xor(ss, m, 64);
    }
    const float mean = s * (1.0f / ED);
    const float var  = ss * (1.0f / ED) - mean * mean;
    const float inv  = rsqrtf(var + 1e-5f);

    const float4 g0  = *(const float4*)(ln_g + l32 * 8);
    const float4 g1  = *(const float4*)(ln_g + l32 * 8 + 4);
    const float4 be0 = *(const float4*)(ln_b + l32 * 8);
    const float4 be1 = *(const float4*)(ln_b + l32 * 8 + 4);

    float4 o0, o1;
    o0.x = (r[0] - mean) * inv * g0.x + be0.x;
    o0.y = (r[1] - mean) * inv * g0.y + be0.y;
    o0.z = (r[2] - mean) * inv * g0.z + be0.z;
    o0.w = (r[3] - mean) * inv * g0.w + be0.w;
    o1.x = (r[4] - mean) * inv * g1.x + be1.x;
    o1.y = (r[5] - mean) * inv * g1.y + be1.y;
    o1.z = (r[6] - mean) * inv * g1.z + be1.z;
    o1.w = (r[7] - mean) * inv * g1.w + be1.w;

    float* op = out + ((size_t)b * nq + q) * ED + l32 * 8;
    *(float4*)op       = o0;
    *(float4*)(op + 4) = o1;
}

extern "C" void kernel_launch(void* const* d_in, const int* in_sizes, int n_in,
                              void* d_out, int out_size, void* d_ws, size_t ws_size,
                              hipStream_t stream)
{
    const float* query  = (const float*)d_in[0];
    const float* feat   = (const float*)d_in[1];
    const float* ref2d  = (const float*)d_in[2];
    const float* W_off  = (const float*)d_in[3];
    const float* b_off  = (const float*)d_in[4];
    const float* W_attn = (const float*)d_in[5];
    const float* b_attn = (const float*)d_in[6];
    const float* ln_g   = (const float*)d_in[7];
    const float* ln_b   = (const float*)d_in[8];
    const int*   Hp     = (const int*)d_in[9];
    const int*   Wp     = (const int*)d_in[10];
    float* out = (float*)d_out;
    float* ws  = (float*)d_ws;

    const int bs = in_sizes[0] / ED;            // 8
    const int nq = in_sizes[2] / (bs * 2);      // h*w = 4096
    const int nfeat = in_sizes[1];              // bs*nq*ED
    const int per_batch8 = nfeat / (bs * 8);    // half8v units per batch

    // ws layout: [0, 1536) floats = precompute; fp16 feat at byte 8192.
    _Float16* feat16 = (_Float16*)((char*)d_ws + 8192);

    convert_kernel<<<bs * 256, 256, 0, stream>>>((const float4*)feat,
                                                 (half8v*)feat16, per_batch8, bs);
    precompute_kernel<<<bs, 256, 0, stream>>>(query, W_off, b_off, W_attn, b_attn, ws);
    deform_attn_kernel<<<bs * nq / QPB, 256, 0, stream>>>((const _Float16*)feat16,
                                                          ref2d, query, ln_g, ln_b,
                                                          ws, Hp, Wp, out, nq, bs);
}

// Round 8
// 134.117 us; speedup vs baseline: 1.0299x; 1.0299x over previous
//
#include <hip/hip_runtime.h>

#define ED 256
#define NHEAD 8
#define NPTS 8
#define DHEAD 32
#define QPB 8   // queries per block: 4 waves x 2 queries (one per 32-lane half)

typedef _Float16 half8v __attribute__((ext_vector_type(8)));

// ---------------------------------------------------------------------------
// Kernel P: fused prep. Blocks [0,bs): per-batch precompute (query broadcast
// -> offsets + softmax weights depend only on batch; ws = off[128],aw[64]).
// Blocks [bs, bs+bs*256): feat fp32 -> fp16, batch-pinned to XCD b so the
// 2MB fp16 map is written into (and stays in) XCD b's L2 for the deform pass.
// ---------------------------------------------------------------------------
__global__ __launch_bounds__(256) void prep_kernel(
    const float4* __restrict__ feat, half8v* __restrict__ feat16,
    int per_batch8,
    const float* __restrict__ query,
    const float* __restrict__ W_off, const float* __restrict__ b_off,
    const float* __restrict__ W_attn, const float* __restrict__ b_attn,
    float* __restrict__ ws, int bs)
{
    const int t = threadIdx.x;

    if ((int)blockIdx.x >= bs) {
        // ---------------- convert role ----------------
        const int cid    = blockIdx.x - bs;
        const int b      = cid % bs;
        const int chunk  = cid / bs;
        const int nchunk = (gridDim.x - bs) / bs;
        const size_t base = (size_t)b * per_batch8;
        for (int i = chunk * 256 + t; i < per_batch8; i += nchunk * 256) {
            const size_t idx = base + i;
            const float4 f0 = feat[2 * idx];
            const float4 f1 = feat[2 * idx + 1];
            half8v h;
            h[0] = (_Float16)f0.x; h[1] = (_Float16)f0.y;
            h[2] = (_Float16)f0.z; h[3] = (_Float16)f0.w;
            h[4] = (_Float16)f1.x; h[5] = (_Float16)f1.y;
            h[6] = (_Float16)f1.z; h[7] = (_Float16)f1.w;
            feat16[idx] = h;
        }
        return;
    }

    // ---------------- precompute role ----------------
    const int b = blockIdx.x;
    __shared__ float sq[ED];
    __shared__ float red[256];
    __shared__ float sattn[64];

    sq[t] = query[b * ED + t];
    __syncthreads();

    {
        const int col  = t & 127;
        const int half = t >> 7;
        const float* Wp = W_off + (size_t)half * 128 * 128 + col;
        const float* qp = sq + half * 128;
        float a0 = 0.f, a1 = 0.f, a2 = 0.f, a3 = 0.f;
        #pragma unroll 8
        for (int k = 0; k < 128; k += 4) {
            a0 = fmaf(qp[k + 0], Wp[(k + 0) * 128], a0);
            a1 = fmaf(qp[k + 1], Wp[(k + 1) * 128], a1);
            a2 = fmaf(qp[k + 2], Wp[(k + 2) * 128], a2);
            a3 = fmaf(qp[k + 3], Wp[(k + 3) * 128], a3);
        }
        red[t] = (a0 + a1) + (a2 + a3);
    }
    __syncthreads();
    if (t < 128) ws[b * 192 + t] = fmaxf(red[t] + red[t + 128] + b_off[t], 0.0f);
    __syncthreads();

    {
        const int col = t & 63;
        const int qtr = t >> 6;
        const float* Wp = W_attn + (size_t)qtr * 64 * 64 + col;
        const float* qp = sq + qtr * 64;
        float a0 = 0.f, a1 = 0.f, a2 = 0.f, a3 = 0.f;
        #pragma unroll 8
        for (int k = 0; k < 64; k += 4) {
            a0 = fmaf(qp[k + 0], Wp[(k + 0) * 64], a0);
            a1 = fmaf(qp[k + 1], Wp[(k + 1) * 64], a1);
            a2 = fmaf(qp[k + 2], Wp[(k + 2) * 64], a2);
            a3 = fmaf(qp[k + 3], Wp[(k + 3) * 64], a3);
        }
        red[t] = (a0 + a1) + (a2 + a3);
    }
    __syncthreads();
    if (t < 64) {
        sattn[t] = fmaxf(red[t] + red[t + 64] + red[t + 128] + red[t + 192]
                         + b_attn[t], 0.0f);
    }
    __syncthreads();
    if (t < 64) {
        const int hh = t >> 3;
        float m = -1e30f;
        #pragma unroll
        for (int p = 0; p < NPTS; ++p) m = fmaxf(m, sattn[hh * NPTS + p]);
        float s = 0.0f;
        #pragma unroll
        for (int p = 0; p < NPTS; ++p) s += expf(sattn[hh * NPTS + p] - m);
        ws[b * 192 + 128 + t] = expf(sattn[t] - m) / s;
    }
}

// ---------------------------------------------------------------------------
// Kernel B v8 = v6 + forced 2-deep load pipeline.
// Compiler always minimizes VGPR (36) and keeps only one load-batch in
// flight (measured: 0.45 lines/cy/CU, ~2x above latency floor across
// R4-R7; launch_bounds alone never changed VGPR). sched_barrier(0) fences
// pin: [issue pp0, pp2][fence][consume pp0, issue pp4][fence][consume pp2,
// issue pp6][fence][consume pp4, pp6] -> 16 loads in flight per wave.
//  - wave = 2 queries (one per 32-lane half); thread = 8 fp16 channels.
//  - LayerNorm reduce over 32 lanes (shfl_xor m<=16 stays in-half).
//  - blockIdx % bs pins batch b to XCD b (matches convert's placement).
// ---------------------------------------------------------------------------
__global__ __launch_bounds__(256, 4) void deform_attn_kernel(
    const _Float16* __restrict__ feat16, // [bs, nq, NHEAD, DHEAD] fp16
    const float* __restrict__ ref2d,     // [bs, nq, 1, 2]
    const float* __restrict__ query,     // [bs, 1, ED]
    const float* __restrict__ ln_g, const float* __restrict__ ln_b,
    const float* __restrict__ ws,        // [bs, 192]
    const int* __restrict__ Hp, const int* __restrict__ Wp,
    float* __restrict__ out,             // [bs, nq, ED]
    int nq, int bs)
{
    const int blk = blockIdx.x;
    const int b = blk % bs;                    // XCD swizzle
    const int qbase = (blk / bs) * QPB;
    const int t = threadIdx.x;

    __shared__ float s_off[128];
    __shared__ float s_aw[64];
    __shared__ float s_ref[QPB * 2];
    __shared__ uint4  s_ofs[QPB * 64];         // [q][p*8+h]: byte offsets
    __shared__ float4 s_wt [QPB * 64];         // [q][p*8+h]: folded weights

    if (t < 128)      s_off[t] = ws[b * 192 + t];
    else if (t < 192) s_aw[t - 128] = ws[b * 192 + t];
    else if (t < 192 + QPB * 2) {
        const int i = t - 192;                 // i = qL*2 + j
        s_ref[i] = ref2d[(b * nq + qbase + (i >> 1)) * 2 + (i & 1)];
    }
    const int H = Hp[0];
    const int W = Wp[0];
    __syncthreads();

    // ---- Phase 1: 8*64 tuples, 2 per thread; entry l -> (p=l>>3, h=l&7) ----
    #pragma unroll
    for (int u = t; u < QPB * 64; u += 256) {
        const int qL = u >> 6;
        const int l  = u & 63;
        const int p  = l >> 3;
        const int h  = l & 7;
        const int hp = h * 8 + p;

        const float x = s_ref[qL * 2 + 0] * (float)W - 0.5f + s_off[hp * 2 + 0];
        const float y = s_ref[qL * 2 + 1] * (float)H - 0.5f + s_off[hp * 2 + 1];
        const float aw = s_aw[hp];

        const float xf = floorf(x);
        const float yf = floorf(y);
        const int ix = (int)xf;
        const int iy = (int)yf;
        const float wx = x - xf;
        const float wy = y - yf;

        const bool vx0 = (ix >= 0) && (ix < W);
        const bool vx1 = (ix + 1 >= 0) && (ix + 1 < W);
        const bool vy0 = (iy >= 0) && (iy < H);
        const bool vy1 = (iy + 1 >= 0) && (iy + 1 < H);
        const int cx0 = min(max(ix, 0), W - 1);
        const int cx1 = min(max(ix + 1, 0), W - 1);
        const int cy0 = min(max(iy, 0), H - 1);
        const int cy1 = min(max(iy + 1, 0), H - 1);

        const int r0 = cy0 * W;
        const int r1 = cy1 * W;
        uint4 ofs;                              // byte offsets, pos stride 512B
        ofs.x = (unsigned)(r0 + cx0) << 9;
        ofs.y = (unsigned)(r0 + cx1) << 9;
        ofs.z = (unsigned)(r1 + cx0) << 9;
        ofs.w = (unsigned)(r1 + cx1) << 9;

        const float awx = aw * wx, awix = aw - awx;     // aw*(1-wx)
        float4 wt;
        wt.x = (vx0 && vy0) ? awix * (1.0f - wy) : 0.0f;
        wt.y = (vx1 && vy0) ? awx  * (1.0f - wy) : 0.0f;
        wt.z = (vx0 && vy1) ? awix * wy          : 0.0f;
        wt.w = (vx1 && vy1) ? awx  * wy          : 0.0f;

        s_ofs[u] = ofs;
        s_wt[u]  = wt;
    }
    __syncthreads();

    // ---- Phase 2: forced-pipeline gather. wave = 2 queries ----
    const int wave = t >> 6;
    const int lane = t & 63;
    const int half = lane >> 5;
    const int l32  = lane & 31;
    const int h    = l32 >> 2;                 // head
    const int c16  = l32 & 3;                  // 16B chunk within 64B slice
    const int qloc = wave * 2 + half;
    const int q    = qbase + qloc;
    const int cb   = qloc * 64 + h;            // + p*8 per point

    const char* fb = (const char*)feat16 + (size_t)b * nq * (NHEAD * DHEAD * 2);
    const unsigned laneofs = (unsigned)(h * 64 + c16 * 16);

    // epilogue operands issued early (independent of gather)
    const float4 qv0 = *(const float4*)(query + b * ED + l32 * 8);
    const float4 qv1 = *(const float4*)(query + b * ED + l32 * 8 + 4);
    const float4 g0  = *(const float4*)(ln_g + l32 * 8);
    const float4 g1  = *(const float4*)(ln_g + l32 * 8 + 4);
    const float4 be0 = *(const float4*)(ln_b + l32 * 8);
    const float4 be1 = *(const float4*)(ln_b + l32 * 8 + 4);

    float acc[8] = {0.f, 0.f, 0.f, 0.f, 0.f, 0.f, 0.f, 0.f};

#define ISSUE(P, pp) \
    const uint4  iA##P = s_ofs[cb + (pp) * 8]; \
    const float4 wA##P = s_wt [cb + (pp) * 8]; \
    const uint4  iB##P = s_ofs[cb + (pp) * 8 + 8]; \
    const float4 wB##P = s_wt [cb + (pp) * 8 + 8]; \
    const half8v A0##P = *(const half8v*)(fb + (iA##P.x + laneofs)); \
    const half8v A1##P = *(const half8v*)(fb + (iA##P.y + laneofs)); \
    const half8v A2##P = *(const half8v*)(fb + (iA##P.z + laneofs)); \
    const half8v A3##P = *(const half8v*)(fb + (iA##P.w + laneofs)); \
    const half8v B0##P = *(const half8v*)(fb + (iB##P.x + laneofs)); \
    const half8v B1##P = *(const half8v*)(fb + (iB##P.y + laneofs)); \
    const half8v B2##P = *(const half8v*)(fb + (iB##P.z + laneofs)); \
    const half8v B3##P = *(const half8v*)(fb + (iB##P.w + laneofs));

#define CONSUME(P) \
    _Pragma("unroll") \
    for (int j = 0; j < 8; ++j) { \
        acc[j] = fmaf(wA##P.x, (float)A0##P[j], acc[j]); \
        acc[j] = fmaf(wA##P.y, (float)A1##P[j], acc[j]); \
        acc[j] = fmaf(wA##P.z, (float)A2##P[j], acc[j]); \
        acc[j] = fmaf(wA##P.w, (float)A3##P[j], acc[j]); \
        acc[j] = fmaf(wB##P.x, (float)B0##P[j], acc[j]); \
        acc[j] = fmaf(wB##P.y, (float)B1##P[j], acc[j]); \
        acc[j] = fmaf(wB##P.z, (float)B2##P[j], acc[j]); \
        acc[j] = fmaf(wB##P.w, (float)B3##P[j], acc[j]); \
    }

    ISSUE(0, 0)
    ISSUE(1, 2)
    __builtin_amdgcn_sched_barrier(0);
    CONSUME(0)
    ISSUE(2, 4)
    __builtin_amdgcn_sched_barrier(0);
    CONSUME(1)
    ISSUE(3, 6)
    __builtin_amdgcn_sched_barrier(0);
    CONSUME(2)
    CONSUME(3)

#undef ISSUE
#undef CONSUME

    // ---- Phase 3: residual + half-wave (32-lane) LayerNorm ----
    float r[8];
    r[0] = acc[0] + qv0.x; r[1] = acc[1] + qv0.y;
    r[2] = acc[2] + qv0.z; r[3] = acc[3] + qv0.w;
    r[4] = acc[4] + qv1.x; r[5] = acc[5] + qv1.y;
    r[6] = acc[6] + qv1.z; r[7] = acc[7] + qv1.w;

    float s = 0.f, ss = 0.f;
    #pragma unroll
    for (int j = 0; j < 8; ++j) {
        s += r[j];
        ss = fmaf(r[j], r[j], ss);
    }
    #pragma unroll
    for (int m = 1; m < 32; m <<= 1) {         // stays within 32-lane half
        s  += __shfl_xor(s, m, 64);
        ss += __shfl_xor(ss, m, 64);
    }
    const float mean = s * (1.0f / ED);
    const float var  = ss * (1.0f / ED) - mean * mean;
    const float inv  = rsqrtf(var + 1e-5f);

    float4 o0, o1;
    o0.x = (r[0] - mean) * inv * g0.x + be0.x;
    o0.y = (r[1] - mean) * inv * g0.y + be0.y;
    o0.z = (r[2] - mean) * inv * g0.z + be0.z;
    o0.w = (r[3] - mean) * inv * g0.w + be0.w;
    o1.x = (r[4] - mean) * inv * g1.x + be1.x;
    o1.y = (r[5] - mean) * inv * g1.y + be1.y;
    o1.z = (r[6] - mean) * inv * g1.z + be1.z;
    o1.w = (r[7] - mean) * inv * g1.w + be1.w;

    float* op = out + ((size_t)b * nq + q) * ED + l32 * 8;
    *(float4*)op       = o0;
    *(float4*)(op + 4) = o1;
}

extern "C" void kernel_launch(void* const* d_in, const int* in_sizes, int n_in,
                              void* d_out, int out_size, void* d_ws, size_t ws_size,
                              hipStream_t stream)
{
    const float* query  = (const float*)d_in[0];
    const float* feat   = (const float*)d_in[1];
    const float* ref2d  = (const float*)d_in[2];
    const float* W_off  = (const float*)d_in[3];
    const float* b_off  = (const float*)d_in[4];
    const float* W_attn = (const float*)d_in[5];
    const float* b_attn = (const float*)d_in[6];
    const float* ln_g   = (const float*)d_in[7];
    const float* ln_b   = (const float*)d_in[8];
    const int*   Hp     = (const int*)d_in[9];
    const int*   Wp     = (const int*)d_in[10];
    float* out = (float*)d_out;
    float* ws  = (float*)d_ws;

    const int bs = in_sizes[0] / ED;            // 8
    const int nq = in_sizes[2] / (bs * 2);      // h*w = 4096
    const int nfeat = in_sizes[1];              // bs*nq*ED
    const int per_batch8 = nfeat / (bs * 8);    // half8v units per batch

    // ws layout: [0, 1536) floats = precompute; fp16 feat at byte 8192.
    _Float16* feat16 = (_Float16*)((char*)d_ws + 8192);

    prep_kernel<<<bs + bs * 256, 256, 0, stream>>>(
        (const float4*)feat, (half8v*)feat16, per_batch8,
        query, W_off, b_off, W_attn, b_attn, ws, bs);
    deform_attn_kernel<<<bs * nq / QPB, 256, 0, stream>>>((const _Float16*)feat16,
                                                          ref2d, query, ln_g, ln_b,
                                                          ws, Hp, Wp, out, nq, bs);
}